// Round 5
// baseline (782.767 us; speedup 1.0000x reference)
//
#include <hip/hip_runtime.h>
#include <hip/hip_bf16.h>

#define NN 50000
#define NE 800000
#define D 128

#define RPB 64            // rows per bucket (power of two: row>>6)
#define NB 782            // ceil(NN / RPB); 4 blocks/CU -> one round
#define CAP 1408          // records per bucket: mean 1024, +12 sigma
#define TILE 4096         // edges per bin block
#define NBIN 196          // ceil(NE/TILE)
#define FSTR 132          // f32 accum tile row stride (dwords): 16B-aligned, banks+4
#define CURN 1024         // cursor array size (padded)

#define CASTB 1563        // ceil(800000 / 512) uint4-casts of x
#define PACKB 4           // 2048 threads / 512

// ws layout in dwords
#define XH_OFF   0                   // x_h bf16: 3,200,000 dwords
#define WF_OFF   3200000             // Wf: 8192 dwords
#define CUR_OFF  3208192             // CURN cursors
#define REC_OFF  3209216             // records: NB*CAP int2 = 2,202,112 dwords

typedef short bf16x8 __attribute__((ext_vector_type(8)));
typedef float f32x4 __attribute__((ext_vector_type(4)));

__device__ inline unsigned short f2bf_u(float f) {
    __hip_bfloat16 h = __float2bfloat16(f);   // RNE
    return __builtin_bit_cast(unsigned short, h);
}
__device__ inline unsigned pack2(float a, float b) {
    return (unsigned)f2bf_u(a) | ((unsigned)f2bf_u(b) << 16);
}

// scatter one record into the LDS f32 accumulator tile (8 ds_add_f32)
__device__ inline void scat(float* ftile, int2 e, uint4 v, int q) {
    int row = (((unsigned)e.x) >> 16) & (RPB - 1);
    float w = __int_as_float(e.y);
    float* dst = &ftile[row * FSTR + q * 8];
    unsigned dw[4] = {v.x, v.y, v.z, v.w};
    #pragma unroll
    for (int i = 0; i < 4; ++i) {
        atomicAdd(&dst[2 * i],     w * __int_as_float((int)(dw[i] << 16)));
        atomicAdd(&dst[2 * i + 1], w * __int_as_float((int)(dw[i] & 0xffff0000u)));
    }
}

// ---------------------------------------------------------------------------
// 1) fused grid, bin blocks FIRST (overlap with cast):
//    [0,NBIN): bin edges -> LDS hist -> global reserve -> direct scatter.
//      (record order within a bucket is irrelevant now - no sort downstream)
//    [NBIN,+PACKB): pack W B-frag | [..+CASTB): cast x -> bf16.
//    cursor[] zeroed by a prior hipMemsetAsync.
// ---------------------------------------------------------------------------
__global__ __launch_bounds__(512) void cast_bin_kernel(
    const float* __restrict__ x, const float* __restrict__ W,
    const int* __restrict__ erow, const int* __restrict__ ecol,
    const float* __restrict__ ew,
    unsigned* __restrict__ x_h4, unsigned short* __restrict__ Wf,
    int* __restrict__ cursor, int2* __restrict__ recs)
{
    __shared__ int lhist[CURN];

    int b = blockIdx.x;
    int t = threadIdx.x;

    if (b < NBIN) {
        lhist[t] = 0;
        lhist[t + 512] = 0;
        __syncthreads();

        int base = b * TILE;
        int4 r[2], c[2]; float4 w[2]; bool val[2];
        #pragma unroll
        for (int g = 0; g < 2; ++g) {
            int i4 = (base >> 2) + t + g * 512;
            val[g] = (i4 * 4) < NE;
            if (val[g]) {
                r[g] = ((const int4*)erow)[i4];
                c[g] = ((const int4*)ecol)[i4];
                w[g] = ((const float4*)ew)[i4];
            }
        }
        #pragma unroll
        for (int g = 0; g < 2; ++g) {
            if (val[g]) {
                atomicAdd(&lhist[(unsigned)r[g].x >> 6], 1);
                atomicAdd(&lhist[(unsigned)r[g].y >> 6], 1);
                atomicAdd(&lhist[(unsigned)r[g].z >> 6], 1);
                atomicAdd(&lhist[(unsigned)r[g].w >> 6], 1);
            }
        }
        __syncthreads();

        // reserve: lhist[bin] becomes this block's global base cursor
        #pragma unroll
        for (int k = 0; k < 2; ++k) {
            int bin = t + k * 512;
            int n = lhist[bin];
            if (n > 0) lhist[bin] = atomicAdd(&cursor[bin], n);
        }
        __syncthreads();

        #pragma unroll
        for (int g = 0; g < 2; ++g) {
            if (val[g]) {
                int rr[4] = {r[g].x, r[g].y, r[g].z, r[g].w};
                int cc[4] = {c[g].x, c[g].y, c[g].z, c[g].w};
                float wwv[4] = {w[g].x, w[g].y, w[g].z, w[g].w};
                #pragma unroll
                for (int j = 0; j < 4; ++j) {
                    int bk = (unsigned)rr[j] >> 6;
                    int pos = atomicAdd(&lhist[bk], 1);
                    if (pos < CAP) {
                        int2 rec;
                        rec.x = (rr[j] << 16) | cc[j];
                        rec.y = __float_as_int(wwv[j]);
                        recs[(size_t)bk * CAP + pos] = rec;
                    }
                }
            }
        }
        return;
    }

    if (b < NBIN + PACKB) {
        // Wf[(nt*4+c)*64+lane] : element j -> W[c*32+(lane>>4)*8+j][nt*16+(lane&15)]
        int flat = (b - NBIN) * 512 + t;      // [0, 2048)
        int lane = flat & 63;
        int c    = (flat >> 6) & 3;
        int nt   = flat >> 8;
        int col  = nt * 16 + (lane & 15);
        int kb   = c * 32 + (lane >> 4) * 8;
        unsigned d[4];
        #pragma unroll
        for (int jj = 0; jj < 4; ++jj) {
            float a  = W[(kb + 2 * jj) * D + col];
            float bb = W[(kb + 2 * jj + 1) * D + col];
            d[jj] = pack2(a, bb);
        }
        uint4 o; o.x = d[0]; o.y = d[1]; o.z = d[2]; o.w = d[3];
        ((uint4*)Wf)[flat] = o;
        return;
    }

    // ---- cast branch ----
    int idx = (b - NBIN - PACKB) * 512 + t;    // [0, 800000)
    if (idx < 800000) {
        const float4* x4 = (const float4*)x;
        float4 v0 = x4[idx * 2];
        float4 v1 = x4[idx * 2 + 1];
        uint4 o;
        o.x = pack2(v0.x, v0.y);
        o.y = pack2(v0.z, v0.w);
        o.z = pack2(v1.x, v1.y);
        o.w = pack2(v1.z, v1.w);
        ((uint4*)x_h4)[idx] = o;
    }
}

// ---------------------------------------------------------------------------
// 2) per-bucket (64 rows): NO sort. Stream records; each 16-lane group
//    gathers one x_h row (256B) and atomically accumulates w*x into an LDS
//    f32 tile at row&63. Unroll 4 for MLP. Then MFMA epilogue converts
//    f32 tile fragments -> bf16 on the fly. 33.8KB LDS -> 4 blocks/CU,
//    32 waves/CU (one co-resident round at NB=782).
// ---------------------------------------------------------------------------
__global__ __launch_bounds__(512, 8) void agg_gemm_kernel(
    const unsigned short* __restrict__ x_h, const int2* __restrict__ recs,
    const int* __restrict__ cursor, const unsigned short* __restrict__ Wf,
    const float* __restrict__ bias, float* __restrict__ out)
{
    __shared__ float ftile[RPB * FSTR];          // 33.8 KB

    int t = threadIdx.x;
    int b = blockIdx.x;
    int cnt = cursor[b];
    if (cnt > CAP) cnt = CAP;
    const int2* my = recs + (size_t)b * CAP;
    int rb = b * RPB;

    for (int i = t; i < RPB * FSTR; i += 512) ftile[i] = 0.f;
    __syncthreads();

    int q = t & 15;            // D-slice lane (16B of the 256B row)
    int g = t >> 4;            // group id, 32 groups
    const uint4* xv = (const uint4*)x_h;   // one x row = 16 uint4

    int i = g;
    for (; i + 96 < cnt; i += 128) {
        int2 e0 = my[i];
        int2 e1 = my[i + 32];
        int2 e2 = my[i + 64];
        int2 e3 = my[i + 96];
        uint4 w0 = xv[(size_t)(e0.x & 0xffff) * 16 + q];
        uint4 w1 = xv[(size_t)(e1.x & 0xffff) * 16 + q];
        uint4 w2 = xv[(size_t)(e2.x & 0xffff) * 16 + q];
        uint4 w3 = xv[(size_t)(e3.x & 0xffff) * 16 + q];
        scat(ftile, e0, w0, q);
        scat(ftile, e1, w1, q);
        scat(ftile, e2, w2, q);
        scat(ftile, e3, w3, q);
    }
    for (; i < cnt; i += 32) {
        int2 e = my[i];
        uint4 w = xv[(size_t)(e.x & 0xffff) * 16 + q];
        scat(ftile, e, w, q);
    }
    __syncthreads();

    // MFMA epilogue: 8 waves x (16-col ntile) x 4 mtiles; convert f32->bf16
    // per fragment (same single-RNE-round numerics as the old bf16 tile).
    int wave = t >> 6, lane = t & 63;
    int m = lane & 15, quad = lane >> 4;
    const bf16x8* bp = (const bf16x8*)Wf;
    bf16x8 bfr[4];
    #pragma unroll
    for (int c = 0; c < 4; ++c) bfr[c] = bp[(wave * 4 + c) * 64 + lane];
    float bcol = bias[wave * 16 + m];

    #pragma unroll
    for (int mt = 0; mt < 4; ++mt) {
        f32x4 acc = {0.f, 0.f, 0.f, 0.f};
        #pragma unroll
        for (int c = 0; c < 4; ++c) {
            const float4* src = (const float4*)&ftile[(mt * 16 + m) * FSTR + c * 32 + quad * 8];
            float4 f0 = src[0];
            float4 f1 = src[1];
            union { unsigned u[4]; bf16x8 v; } cv;
            cv.u[0] = pack2(f0.x, f0.y);
            cv.u[1] = pack2(f0.z, f0.w);
            cv.u[2] = pack2(f1.x, f1.y);
            cv.u[3] = pack2(f1.z, f1.w);
            acc = __builtin_amdgcn_mfma_f32_16x16x32_bf16(cv.v, bfr[c], acc, 0, 0, 0);
        }
        #pragma unroll
        for (int r = 0; r < 4; ++r) {
            int lr = mt * 16 + quad * 4 + r;
            int grow = rb + lr;
            if (grow < NN)
                out[(size_t)grow * D + wave * 16 + m] = acc[r] + bcol;
        }
    }
}

extern "C" void kernel_launch(void* const* d_in, const int* in_sizes, int n_in,
                              void* d_out, int out_size, void* d_ws, size_t ws_size,
                              hipStream_t stream) {
    const float* x    = (const float*)d_in[0];
    const float* W    = (const float*)d_in[1];
    const float* bias = (const float*)d_in[2];
    const float* ew   = (const float*)d_in[3];
    const int*   erow = (const int*)d_in[4];
    const int*   ecol = (const int*)d_in[5];
    float* out = (float*)d_out;

    unsigned* ws_u = (unsigned*)d_ws;
    unsigned*        x_h4   = ws_u + XH_OFF;
    unsigned short*  x_h    = (unsigned short*)x_h4;
    unsigned short*  Wf     = (unsigned short*)(ws_u + WF_OFF);
    int*             cursor = (int*)(ws_u + CUR_OFF);
    int2*            recs   = (int2*)(ws_u + REC_OFF);

    hipMemsetAsync(cursor, 0, CURN * sizeof(int), stream);
    cast_bin_kernel<<<NBIN + PACKB + CASTB, 512, 0, stream>>>(
        x, W, erow, ecol, ew, x_h4, Wf, cursor, recs);
    agg_gemm_kernel<<<NB, 512, 0, stream>>>(x_h, recs, cursor, Wf, bias, out);
}

// Round 6
// 130.606 us; speedup vs baseline: 5.9933x; 5.9933x over previous
//
#include <hip/hip_runtime.h>
#include <hip/hip_bf16.h>

#define NN 50000
#define NE 800000
#define D 128

#define RPB 128           // rows per bucket (power of two: row>>7)
#define NB 391            // ceil(NN / RPB)
#define CAP 2560          // records per bucket: mean 2046, +11 sigma
#define TILE 8192         // edges per bin block
#define NBIN 98           // ceil(NE/TILE)
#define TSTR 136          // bf16 tile row stride (halves): 272B, 16B-aligned
#define CURN 512          // cursor array size (padded, bins < 391)

#define CASTB 1563        // ceil(800000 / 512) uint4-casts of x
#define PACKB 4           // 2048 threads / 512

// ws layout in dwords
#define XH_OFF   0                   // x_h bf16: 3,200,000 dwords
#define WF_OFF   3200000             // Wf: 8192 dwords
#define CUR_OFF  3208192             // CURN cursors
#define REC_OFF  3209216             // records: NB*CAP int2 = 2,001,920 dwords

typedef short bf16x8 __attribute__((ext_vector_type(8)));
typedef float f32x4 __attribute__((ext_vector_type(4)));

__device__ inline unsigned short f2bf_u(float f) {
    __hip_bfloat16 h = __float2bfloat16(f);   // RNE
    return __builtin_bit_cast(unsigned short, h);
}
__device__ inline unsigned pack2(float a, float b) {
    return (unsigned)f2bf_u(a) | ((unsigned)f2bf_u(b) << 16);
}
__device__ inline void acc8(float* acc, uint4 v, float w) {
    unsigned dw[4] = {v.x, v.y, v.z, v.w};
    #pragma unroll
    for (int i = 0; i < 4; ++i) {
        float lo = __int_as_float((int)(dw[i] << 16));
        float hi = __int_as_float((int)(dw[i] & 0xffff0000u));
        acc[2 * i]     += w * lo;
        acc[2 * i + 1] += w * hi;
    }
}

// ---------------------------------------------------------------------------
// 1) fused grid, bin blocks FIRST:
//    [0,NBIN): bin edges -> 2KB LDS hist -> global reserve -> direct scatter
//      (3 barriers, no scan, no staging; record order within a bucket is
//      irrelevant because k2 sorts by row itself). int LDS atomics only.
//    [NBIN,+PACKB): pack W B-frag | [..+CASTB): cast x -> bf16.
//    Static LDS is 2KB -> cast blocks keep full occupancy.
//    cursor[] zeroed by a prior hipMemsetAsync.
// ---------------------------------------------------------------------------
__global__ __launch_bounds__(512) void cast_bin_kernel(
    const float* __restrict__ x, const float* __restrict__ W,
    const int* __restrict__ erow, const int* __restrict__ ecol,
    const float* __restrict__ ew,
    unsigned* __restrict__ x_h4, unsigned short* __restrict__ Wf,
    int* __restrict__ cursor, int2* __restrict__ recs)
{
    __shared__ int lhist[CURN];          // 2 KB

    int b = blockIdx.x;
    int t = threadIdx.x;

    if (b < NBIN) {
        lhist[t] = 0;                    // CURN == 512 == blockDim
        __syncthreads();

        int base = b * TILE;             // TILE = 8192 edges, 16/thread
        int4 r[4], c[4]; float4 w[4]; bool val[4];
        #pragma unroll
        for (int g = 0; g < 4; ++g) {
            int i4 = (base >> 2) + t + g * 512;
            val[g] = (i4 * 4) < NE;
            if (val[g]) {
                r[g] = ((const int4*)erow)[i4];
                c[g] = ((const int4*)ecol)[i4];
                w[g] = ((const float4*)ew)[i4];
            }
        }
        #pragma unroll
        for (int g = 0; g < 4; ++g) {
            if (val[g]) {
                atomicAdd(&lhist[(unsigned)r[g].x >> 7], 1);
                atomicAdd(&lhist[(unsigned)r[g].y >> 7], 1);
                atomicAdd(&lhist[(unsigned)r[g].z >> 7], 1);
                atomicAdd(&lhist[(unsigned)r[g].w >> 7], 1);
            }
        }
        __syncthreads();

        // reserve: lhist[bin] becomes this block's global base cursor
        {
            int n = lhist[t];
            if (n > 0) lhist[t] = atomicAdd(&cursor[t], n);
        }
        __syncthreads();

        #pragma unroll
        for (int g = 0; g < 4; ++g) {
            if (val[g]) {
                int rr[4] = {r[g].x, r[g].y, r[g].z, r[g].w};
                int cc[4] = {c[g].x, c[g].y, c[g].z, c[g].w};
                float wwv[4] = {w[g].x, w[g].y, w[g].z, w[g].w};
                #pragma unroll
                for (int j = 0; j < 4; ++j) {
                    int bk = (unsigned)rr[j] >> 7;
                    int pos = atomicAdd(&lhist[bk], 1);
                    if (pos < CAP) {
                        int2 rec;
                        rec.x = (rr[j] << 16) | cc[j];
                        rec.y = __float_as_int(wwv[j]);
                        recs[(size_t)bk * CAP + pos] = rec;
                    }
                }
            }
        }
        return;
    }

    if (b < NBIN + PACKB) {
        // Wf[(nt*4+c)*64+lane] : element j -> W[c*32+(lane>>4)*8+j][nt*16+(lane&15)]
        int flat = (b - NBIN) * 512 + t;      // [0, 2048)
        int lane = flat & 63;
        int c    = (flat >> 6) & 3;
        int nt   = flat >> 8;
        int col  = nt * 16 + (lane & 15);
        int kb   = c * 32 + (lane >> 4) * 8;
        unsigned d[4];
        #pragma unroll
        for (int jj = 0; jj < 4; ++jj) {
            float a  = W[(kb + 2 * jj) * D + col];
            float bb = W[(kb + 2 * jj + 1) * D + col];
            d[jj] = pack2(a, bb);
        }
        uint4 o; o.x = d[0]; o.y = d[1]; o.z = d[2]; o.w = d[3];
        ((uint4*)Wf)[flat] = o;
        return;
    }

    // ---- cast branch ----
    int idx = (b - NBIN - PACKB) * 512 + t;    // [0, 800000)
    if (idx < 800000) {
        const float4* x4 = (const float4*)x;
        float4 v0 = x4[idx * 2];
        float4 v1 = x4[idx * 2 + 1];
        uint4 o;
        o.x = pack2(v0.x, v0.y);
        o.y = pack2(v0.z, v0.w);
        o.z = pack2(v1.x, v1.y);
        o.w = pack2(v1.z, v1.w);
        ((uint4*)x_h4)[idx] = o;
    }
}

// ---------------------------------------------------------------------------
// 2) per-bucket (128 rows): records -> registers (5 passes) -> LDS
//    counting-sort by row (2-wave shfl scan, 128 bins) -> register gather
//    (16 lanes/node, 32 groups x 4 rows, 8 loads in flight) -> bf16 LDS
//    tile -> MFMA GEMM (8 mtiles) + bias -> out.  [R4-proven verbatim]
// ---------------------------------------------------------------------------
__global__ __launch_bounds__(512, 4) void gat_gemm_kernel(
    const unsigned short* __restrict__ x_h, const int2* __restrict__ recs,
    const int* __restrict__ cursor, const unsigned short* __restrict__ Wf,
    const float* __restrict__ bias, float* __restrict__ out)
{
    __shared__ int2 srec[CAP];                                   // 20 KB
    __shared__ __align__(16) unsigned short tile[RPB * TSTR];    // 34.8 KB
    __shared__ int rowstart[RPB + 1];
    __shared__ int rowcur[RPB];
    __shared__ int wtot;

    int t = threadIdx.x;
    int b = blockIdx.x;
    int cnt = cursor[b];
    if (cnt > CAP) cnt = CAP;
    const int2* my = recs + (size_t)b * CAP;
    int rb = b * RPB;

    if (t < RPB) rowcur[t] = 0;
    __syncthreads();

    // records -> registers (coalesced int2, 5 conditional passes)
    int2 rr[5];
    bool vv[5];
    #pragma unroll
    for (int k = 0; k < 5; ++k) {
        int i = t + k * 512;
        vv[k] = i < cnt;
        if (vv[k]) rr[k] = my[i];
    }
    #pragma unroll
    for (int k = 0; k < 5; ++k)
        if (vv[k]) atomicAdd(&rowcur[(((unsigned)rr[k].x) >> 16) & (RPB - 1)], 1);
    __syncthreads();

    // exclusive scan of 128 row counts: 2 waves, shfl within + LDS combine
    if (t < RPB) {
        int myc = rowcur[t];
        int s = myc;
        #pragma unroll
        for (int off = 1; off < 64; off <<= 1) {
            int v = __shfl_up(s, off);
            if ((t & 63) >= off) s += v;
        }
        if (t == 63) wtot = s;
        __syncthreads();
        if (t >= 64) s += wtot;
        rowstart[t] = s - myc;
        rowcur[t]   = s - myc;
    } else {
        __syncthreads();
    }
    if (t == 0) rowstart[RPB] = cnt;
    __syncthreads();

    // rank + scatter into srec (sorted by row)
    #pragma unroll
    for (int k = 0; k < 5; ++k)
        if (vv[k]) srec[atomicAdd(&rowcur[(((unsigned)rr[k].x) >> 16) & (RPB - 1)], 1)] = rr[k];
    __syncthreads();

    // gather: 16 lanes per node, 32 groups x 4 rows, 8 loads in flight
    int q = t & 15;
    int grp = t >> 4;
    const uint4* xv = (const uint4*)x_h;   // one x row = 16 uint4
    #pragma unroll
    for (int it = 0; it < 4; ++it) {
        int rl = it * 32 + grp;
        int p = rowstart[rl], p1 = rowstart[rl + 1];
        float acc[8] = {};
        for (; p + 8 <= p1; p += 8) {
            int2 e0 = srec[p];
            int2 e1 = srec[p + 1];
            int2 e2 = srec[p + 2];
            int2 e3 = srec[p + 3];
            int2 e4 = srec[p + 4];
            int2 e5 = srec[p + 5];
            int2 e6 = srec[p + 6];
            int2 e7 = srec[p + 7];
            uint4 w0 = xv[(size_t)(e0.x & 0xffff) * 16 + q];
            uint4 w1 = xv[(size_t)(e1.x & 0xffff) * 16 + q];
            uint4 w2 = xv[(size_t)(e2.x & 0xffff) * 16 + q];
            uint4 w3 = xv[(size_t)(e3.x & 0xffff) * 16 + q];
            uint4 w4 = xv[(size_t)(e4.x & 0xffff) * 16 + q];
            uint4 w5 = xv[(size_t)(e5.x & 0xffff) * 16 + q];
            uint4 w6 = xv[(size_t)(e6.x & 0xffff) * 16 + q];
            uint4 w7 = xv[(size_t)(e7.x & 0xffff) * 16 + q];
            acc8(acc, w0, __int_as_float(e0.y));
            acc8(acc, w1, __int_as_float(e1.y));
            acc8(acc, w2, __int_as_float(e2.y));
            acc8(acc, w3, __int_as_float(e3.y));
            acc8(acc, w4, __int_as_float(e4.y));
            acc8(acc, w5, __int_as_float(e5.y));
            acc8(acc, w6, __int_as_float(e6.y));
            acc8(acc, w7, __int_as_float(e7.y));
        }
        for (; p + 4 <= p1; p += 4) {
            int2 e0 = srec[p];
            int2 e1 = srec[p + 1];
            int2 e2 = srec[p + 2];
            int2 e3 = srec[p + 3];
            uint4 w0 = xv[(size_t)(e0.x & 0xffff) * 16 + q];
            uint4 w1 = xv[(size_t)(e1.x & 0xffff) * 16 + q];
            uint4 w2 = xv[(size_t)(e2.x & 0xffff) * 16 + q];
            uint4 w3 = xv[(size_t)(e3.x & 0xffff) * 16 + q];
            acc8(acc, w0, __int_as_float(e0.y));
            acc8(acc, w1, __int_as_float(e1.y));
            acc8(acc, w2, __int_as_float(e2.y));
            acc8(acc, w3, __int_as_float(e3.y));
        }
        for (; p < p1; ++p) {
            int2 e = srec[p];
            uint4 w = xv[(size_t)(e.x & 0xffff) * 16 + q];
            acc8(acc, w, __int_as_float(e.y));
        }
        uint4 o;
        o.x = pack2(acc[0], acc[1]);
        o.y = pack2(acc[2], acc[3]);
        o.z = pack2(acc[4], acc[5]);
        o.w = pack2(acc[6], acc[7]);
        *(uint4*)&tile[rl * TSTR + q * 8] = o;
    }
    __syncthreads();

    // MFMA tail: 8 waves x (16-col ntile) x 8 mtiles; guarded by grow<NN.
    int wave = t >> 6, lane = t & 63;
    int m = lane & 15, quad = lane >> 4;
    const bf16x8* bp = (const bf16x8*)Wf;
    bf16x8 bfr[4];
    #pragma unroll
    for (int c = 0; c < 4; ++c) bfr[c] = bp[(wave * 4 + c) * 64 + lane];
    float bcol = bias[wave * 16 + m];

    #pragma unroll
    for (int mt = 0; mt < 8; ++mt) {
        f32x4 acc = {0.f, 0.f, 0.f, 0.f};
        #pragma unroll
        for (int c = 0; c < 4; ++c) {
            bf16x8 afr = *(const bf16x8*)&tile[(mt * 16 + m) * TSTR + c * 32 + quad * 8];
            acc = __builtin_amdgcn_mfma_f32_16x16x32_bf16(afr, bfr[c], acc, 0, 0, 0);
        }
        #pragma unroll
        for (int r = 0; r < 4; ++r) {
            int lr = mt * 16 + quad * 4 + r;
            int grow = rb + lr;
            if (grow < NN)
                out[(size_t)grow * D + wave * 16 + m] = acc[r] + bcol;
        }
    }
}

extern "C" void kernel_launch(void* const* d_in, const int* in_sizes, int n_in,
                              void* d_out, int out_size, void* d_ws, size_t ws_size,
                              hipStream_t stream) {
    const float* x    = (const float*)d_in[0];
    const float* W    = (const float*)d_in[1];
    const float* bias = (const float*)d_in[2];
    const float* ew   = (const float*)d_in[3];
    const int*   erow = (const int*)d_in[4];
    const int*   ecol = (const int*)d_in[5];
    float* out = (float*)d_out;

    unsigned* ws_u = (unsigned*)d_ws;
    unsigned*        x_h4   = ws_u + XH_OFF;
    unsigned short*  x_h    = (unsigned short*)x_h4;
    unsigned short*  Wf     = (unsigned short*)(ws_u + WF_OFF);
    int*             cursor = (int*)(ws_u + CUR_OFF);
    int2*            recs   = (int2*)(ws_u + REC_OFF);

    hipMemsetAsync(cursor, 0, CURN * sizeof(int), stream);
    cast_bin_kernel<<<NBIN + PACKB + CASTB, 512, 0, stream>>>(
        x, W, erow, ecol, ew, x_h4, Wf, cursor, recs);
    gat_gemm_kernel<<<NB, 512, 0, stream>>>(x_h, recs, cursor, Wf, bias, out);
}